// Round 1
// baseline (380.247 us; speedup 1.0000x reference)
//
#include <hip/hip_runtime.h>
#include <math.h>

#define Bn 4
#define Cn 128
#define Hn 80
#define Wn 80
#define HWn 6400

__device__ __forceinline__ float gelu_exact(float v) {
  return 0.5f * v * (1.f + erff(v * 0.70710678118654752f));
}

// ---------------- LayerNorm over channels (per pixel) ----------------
__global__ __launch_bounds__(256) void ln2d_k(const float* __restrict__ in,
    const float* __restrict__ gw, const float* __restrict__ gb, float* __restrict__ out) {
  __shared__ float sS[4][64];
  __shared__ float sQ[4][64];
  const int b = blockIdx.y;
  const int p0 = blockIdx.x * 64;
  const int px = threadIdx.x & 63;
  const int cg = threadIdx.x >> 6;
  const float* ip = in + (size_t)b * Cn * HWn + p0 + px;
  float s = 0.f, q = 0.f;
  #pragma unroll 8
  for (int c = cg * 32; c < cg * 32 + 32; ++c) {
    float v = ip[(size_t)c * HWn];
    s += v; q += v * v;
  }
  sS[cg][px] = s; sQ[cg][px] = q;
  __syncthreads();
  float S = sS[0][px] + sS[1][px] + sS[2][px] + sS[3][px];
  float Q = sQ[0][px] + sQ[1][px] + sQ[2][px] + sQ[3][px];
  float mu = S * (1.f / 128.f);
  float var = Q * (1.f / 128.f) - mu * mu;
  float rs = rsqrtf(var + 1e-6f);
  float* op = out + (size_t)b * Cn * HWn + p0 + px;
  #pragma unroll 8
  for (int c = cg * 32; c < cg * 32 + 32; ++c) {
    float v = ip[(size_t)c * HWn];
    op[(size_t)c * HWn] = (v - mu) * rs * gw[c] + gb[c];
  }
}

// ---------------- Tiled conv1x1 (GEMM): 64px x 64oc per block ----------------
// MODE 0: out = conv + bias ; MODE 1: out = conv + bias + resid
template<int IC, int MODE>
__global__ __launch_bounds__(256) void conv1x1_k(
    const float* __restrict__ in, const float* __restrict__ w,
    const float* __restrict__ bias, const float* resid,
    float* out, int OCt) {
  __shared__ float sIn[IC * 64];
  __shared__ float sW[IC * 64];
  const int tid = threadIdx.x;
  const int b = blockIdx.y;
  const int p0 = blockIdx.x * 64;
  const int oc0 = blockIdx.z * 64;
  {
    const float* ib = in + (size_t)b * IC * HWn + p0;
    #pragma unroll
    for (int i = tid; i < IC * 16; i += 256) {
      int ic = i >> 4, px4 = (i & 15) << 2;
      *(float4*)&sIn[ic * 64 + px4] = *(const float4*)(ib + (size_t)ic * HWn + px4);
    }
  }
  for (int j = tid; j < IC * 64; j += 256) {
    int oc_l = j / IC, ic = j - oc_l * IC;
    sW[ic * 64 + (((oc_l >> 2) ^ (ic & 15)) << 2) + (oc_l & 3)] =
        w[(size_t)(oc0 + oc_l) * IC + ic];
  }
  __syncthreads();
  const int px4 = (tid & 15) << 2;
  const int ocg = tid >> 4;
  float4 a0 = {0,0,0,0}, a1 = {0,0,0,0}, a2 = {0,0,0,0}, a3 = {0,0,0,0};
  #pragma unroll 4
  for (int ic = 0; ic < IC; ++ic) {
    float4 xi = *(const float4*)&sIn[ic * 64 + px4];
    float4 wq = *(const float4*)&sW[ic * 64 + ((ocg ^ (ic & 15)) << 2)];
    a0.x = fmaf(wq.x, xi.x, a0.x); a0.y = fmaf(wq.x, xi.y, a0.y);
    a0.z = fmaf(wq.x, xi.z, a0.z); a0.w = fmaf(wq.x, xi.w, a0.w);
    a1.x = fmaf(wq.y, xi.x, a1.x); a1.y = fmaf(wq.y, xi.y, a1.y);
    a1.z = fmaf(wq.y, xi.z, a1.z); a1.w = fmaf(wq.y, xi.w, a1.w);
    a2.x = fmaf(wq.z, xi.x, a2.x); a2.y = fmaf(wq.z, xi.y, a2.y);
    a2.z = fmaf(wq.z, xi.z, a2.z); a2.w = fmaf(wq.z, xi.w, a2.w);
    a3.x = fmaf(wq.w, xi.x, a3.x); a3.y = fmaf(wq.w, xi.y, a3.y);
    a3.z = fmaf(wq.w, xi.z, a3.z); a3.w = fmaf(wq.w, xi.w, a3.w);
  }
  const int ocb = oc0 + ocg * 4;
  float4 accs[4] = {a0, a1, a2, a3};
  #pragma unroll
  for (int jj = 0; jj < 4; ++jj) {
    float4 r = accs[jj];
    float bv = bias[ocb + jj];
    r.x += bv; r.y += bv; r.z += bv; r.w += bv;
    size_t idx = ((size_t)b * OCt + ocb + jj) * HWn + p0 + px4;
    if (MODE == 1) {
      float4 rv = *(const float4*)&resid[idx];
      r.x += rv.x; r.y += rv.y; r.z += rv.z; r.w += rv.w;
    }
    *(float4*)&out[idx] = r;
  }
}

// ---------------- QKV conv with gathered weight rows ----------------
// conceptual OC = 384 : oc = sel*128 + c, head = c>>4 ; head<6 -> qkv0, else qkv1
// output layout: [sel][b][c][hw]
__global__ __launch_bounds__(256) void conv_qkv_k(
    const float* __restrict__ in, const float* __restrict__ w0, const float* __restrict__ b0,
    const float* __restrict__ w1, const float* __restrict__ b1, float* __restrict__ qkv) {
  __shared__ float sIn[128 * 64];
  __shared__ float sW[128 * 64];
  const int tid = threadIdx.x;
  const int b = blockIdx.y;
  const int p0 = blockIdx.x * 64;
  const int oc0 = blockIdx.z * 64;
  {
    const float* ib = in + (size_t)b * 128 * HWn + p0;
    #pragma unroll
    for (int i = tid; i < 128 * 16; i += 256) {
      int ic = i >> 4, px4 = (i & 15) << 2;
      *(float4*)&sIn[ic * 64 + px4] = *(const float4*)(ib + (size_t)ic * HWn + px4);
    }
  }
  for (int j = tid; j < 128 * 64; j += 256) {
    int oc_l = j >> 7, ic = j & 127;
    int ocglob = oc0 + oc_l;
    int sel = ocglob >> 7;
    int c = ocglob & 127;
    int head = c >> 4;
    const float* wr = (head < 6 ? w0 : w1) + (size_t)((sel << 7) + c) * 128;
    sW[ic * 64 + (((oc_l >> 2) ^ (ic & 15)) << 2) + (oc_l & 3)] = wr[ic];
  }
  __syncthreads();
  const int px4 = (tid & 15) << 2;
  const int ocg = tid >> 4;
  float4 a0 = {0,0,0,0}, a1 = {0,0,0,0}, a2 = {0,0,0,0}, a3 = {0,0,0,0};
  #pragma unroll 4
  for (int ic = 0; ic < 128; ++ic) {
    float4 xi = *(const float4*)&sIn[ic * 64 + px4];
    float4 wq = *(const float4*)&sW[ic * 64 + ((ocg ^ (ic & 15)) << 2)];
    a0.x = fmaf(wq.x, xi.x, a0.x); a0.y = fmaf(wq.x, xi.y, a0.y);
    a0.z = fmaf(wq.x, xi.z, a0.z); a0.w = fmaf(wq.x, xi.w, a0.w);
    a1.x = fmaf(wq.y, xi.x, a1.x); a1.y = fmaf(wq.y, xi.y, a1.y);
    a1.z = fmaf(wq.y, xi.z, a1.z); a1.w = fmaf(wq.y, xi.w, a1.w);
    a2.x = fmaf(wq.z, xi.x, a2.x); a2.y = fmaf(wq.z, xi.y, a2.y);
    a2.z = fmaf(wq.z, xi.z, a2.z); a2.w = fmaf(wq.z, xi.w, a2.w);
    a3.x = fmaf(wq.w, xi.x, a3.x); a3.y = fmaf(wq.w, xi.y, a3.y);
    a3.z = fmaf(wq.w, xi.z, a3.z); a3.w = fmaf(wq.w, xi.w, a3.w);
  }
  float4 accs[4] = {a0, a1, a2, a3};
  #pragma unroll
  for (int jj = 0; jj < 4; ++jj) {
    int ocglob = oc0 + ocg * 4 + jj;
    int sel = ocglob >> 7;
    int c = ocglob & 127;
    int head = c >> 4;
    float bv = (head < 6 ? b0 : b1)[(sel << 7) + c];
    float4 r = accs[jj];
    r.x += bv; r.y += bv; r.z += bv; r.w += bv;
    size_t idx = (((size_t)sel * Bn + b) * Cn + c) * HWn + p0 + px4;
    *(float4*)&qkv[idx] = r;
  }
}

// ---------------- Neighborhood attention ----------------
template<int KS, int DIL>
__device__ __forceinline__ void natt_body(const float* __restrict__ qkv,
                                          float* __restrict__ out, int b, int h, int p) {
  const int y = p / Wn, x = p - (p / Wn) * Wn;
  const float scale = 0.25f;
  const size_t planeQ = ((size_t)(0 * Bn + b) * Cn + h * 16) * (size_t)HWn;
  const size_t planeK = ((size_t)(1 * Bn + b) * Cn + h * 16) * (size_t)HWn;
  const size_t planeV = ((size_t)(2 * Bn + b) * Cn + h * 16) * (size_t)HWn;
  float qv[16];
  #pragma unroll
  for (int d = 0; d < 16; ++d) qv[d] = qkv[planeQ + (size_t)d * HWn + p] * scale;
  constexpr int L = KS * KS;
  float lg[L];
  #pragma unroll
  for (int i = 0; i < KS; ++i) {
    #pragma unroll
    for (int j = 0; j < KS; ++j) {
      int yy = y + (i - KS / 2) * DIL;
      int xx = x + (j - KS / 2) * DIL;
      float a = 0.f;
      if (yy >= 0 && yy < Hn && xx >= 0 && xx < Wn) {
        int pn = yy * Wn + xx;
        #pragma unroll
        for (int d = 0; d < 16; ++d) a = fmaf(qv[d], qkv[planeK + (size_t)d * HWn + pn], a);
      }
      lg[i * KS + j] = a;
    }
  }
  float mx = lg[0];
  #pragma unroll
  for (int l = 1; l < L; ++l) mx = fmaxf(mx, lg[l]);
  float sum = 0.f;
  #pragma unroll
  for (int l = 0; l < L; ++l) { float e = __expf(lg[l] - mx); lg[l] = e; sum += e; }
  float inv = 1.f / sum;
  float acc[16];
  #pragma unroll
  for (int d = 0; d < 16; ++d) acc[d] = 0.f;
  #pragma unroll
  for (int i = 0; i < KS; ++i) {
    #pragma unroll
    for (int j = 0; j < KS; ++j) {
      int yy = y + (i - KS / 2) * DIL;
      int xx = x + (j - KS / 2) * DIL;
      if (yy >= 0 && yy < Hn && xx >= 0 && xx < Wn) {
        int pn = yy * Wn + xx;
        float wl = lg[i * KS + j] * inv;
        #pragma unroll
        for (int d = 0; d < 16; ++d) acc[d] = fmaf(wl, qkv[planeV + (size_t)d * HWn + pn], acc[d]);
      }
    }
  }
  #pragma unroll
  for (int d = 0; d < 16; ++d)
    out[((size_t)b * Cn + h * 16 + d) * HWn + p] = acc[d];
}

__global__ __launch_bounds__(256) void natt_k(const float* __restrict__ qkv,
                                              float* __restrict__ out) {
  const int b = blockIdx.y;
  const int h = blockIdx.z;
  const int p = blockIdx.x * 256 + threadIdx.x;
  if (h < 6) natt_body<3, 1>(qkv, out, b, h, p);
  else       natt_body<5, 2>(qkv, out, b, h, p);
}

// ---------------- msconvstar: dw + add + gelu-gate ----------------
__device__ __forceinline__ float hh_val(const float* __restrict__ hb, int c, int p, int y, int x,
    const float* __restrict__ w0, const float* __restrict__ b0,
    const float* __restrict__ w1, const float* __restrict__ b1,
    const float* __restrict__ w2, const float* __restrict__ b2) {
  const float* hp = hb + (size_t)c * HWn;
  float center = hp[p];
  if (c < 64) {
    return center + fmaf(center, w0[c], b0[c]);
  } else if (c < 128) {
    int cc = c - 64;
    float acc = b1[cc];
    #pragma unroll
    for (int i = 0; i < 3; ++i) {
      #pragma unroll
      for (int j = 0; j < 3; ++j) {
        int yy = y + i - 1, xx = x + j - 1;
        if (yy >= 0 && yy < Hn && xx >= 0 && xx < Wn)
          acc = fmaf(w1[cc * 9 + i * 3 + j], hp[yy * Wn + xx], acc);
      }
    }
    return center + acc;
  } else {
    int cc = c - 128;
    float acc = b2[cc];
    #pragma unroll
    for (int i = 0; i < 5; ++i) {
      #pragma unroll
      for (int j = 0; j < 5; ++j) {
        int yy = y + i - 2, xx = x + j - 2;
        if (yy >= 0 && yy < Hn && xx >= 0 && xx < Wn)
          acc = fmaf(w2[cc * 25 + i * 5 + j], hp[yy * Wn + xx], acc);
      }
    }
    return center + acc;
  }
}

__global__ __launch_bounds__(256) void star_k(const float* __restrict__ h,
    const float* __restrict__ w0, const float* __restrict__ b0,
    const float* __restrict__ w1, const float* __restrict__ b1,
    const float* __restrict__ w2, const float* __restrict__ b2,
    float* __restrict__ g) {
  const int b = blockIdx.y;
  const int c1 = blockIdx.z;           // 0..95
  const int p = blockIdx.x * 256 + threadIdx.x;
  const int y = p / Wn, x = p - (p / Wn) * Wn;
  const float* hb = h + (size_t)b * 192 * HWn;
  float h1 = hh_val(hb, c1, p, y, x, w0, b0, w1, b1, w2, b2);
  float h2 = hh_val(hb, c1 + 96, p, y, x, w0, b0, w1, b1, w2, b2);
  g[((size_t)b * 96 + c1) * HWn + p] = gelu_exact(h1) * h2;
}

// ---------------- cascaded sparse: dw3x3(dil) + gelu ----------------
template<int DIL>
__global__ __launch_bounds__(256) void dwg_k(const float* __restrict__ in,
    const float* __restrict__ w, const float* __restrict__ bias, float* __restrict__ out) {
  const int b = blockIdx.y;
  const int c = blockIdx.z;
  const int p = blockIdx.x * 256 + threadIdx.x;
  const int y = p / Wn, x = p - (p / Wn) * Wn;
  const float* ip = in + ((size_t)b * Cn + c) * HWn;
  float acc = bias[c];
  #pragma unroll
  for (int i = 0; i < 3; ++i) {
    #pragma unroll
    for (int j = 0; j < 3; ++j) {
      int yy = y + (i - 1) * DIL, xx = x + (j - 1) * DIL;
      if (yy >= 0 && yy < Hn && xx >= 0 && xx < Wn)
        acc = fmaf(w[c * 9 + i * 3 + j], ip[yy * Wn + xx], acc);
    }
  }
  out[((size_t)b * Cn + c) * HWn + p] = gelu_exact(acc);
}

// ---------------- launch ----------------
extern "C" void kernel_launch(void* const* d_in, const int* in_sizes, int n_in,
                              void* d_out, int out_size, void* d_ws, size_t ws_size,
                              hipStream_t stream) {
  (void)in_sizes; (void)n_in; (void)out_size; (void)ws_size;
  const float* x      = (const float*)d_in[0];
  const float* n1w    = (const float*)d_in[1];
  const float* n1b    = (const float*)d_in[2];
  const float* n2w    = (const float*)d_in[3];
  const float* n2b    = (const float*)d_in[4];
  const float* n3w    = (const float*)d_in[5];
  const float* n3b    = (const float*)d_in[6];
  const float* n4w    = (const float*)d_in[7];
  const float* n4b    = (const float*)d_in[8];
  const float* qkv0w  = (const float*)d_in[9];
  const float* qkv0b  = (const float*)d_in[10];
  const float* qkv1w  = (const float*)d_in[11];
  const float* qkv1b  = (const float*)d_in[12];
  const float* projw  = (const float*)d_in[13];
  const float* projb  = (const float*)d_in[14];
  const float* m1fc1w = (const float*)d_in[15];
  const float* m1fc1b = (const float*)d_in[16];
  const float* m1dw0w = (const float*)d_in[17];
  const float* m1dw0b = (const float*)d_in[18];
  const float* m1dw1w = (const float*)d_in[19];
  const float* m1dw1b = (const float*)d_in[20];
  const float* m1dw2w = (const float*)d_in[21];
  const float* m1dw2b = (const float*)d_in[22];
  const float* m1fc2w = (const float*)d_in[23];
  const float* m1fc2b = (const float*)d_in[24];
  const float* smadw0w = (const float*)d_in[25];
  const float* smadw0b = (const float*)d_in[26];
  const float* smadw1w = (const float*)d_in[27];
  const float* smadw1b = (const float*)d_in[28];
  const float* smapww  = (const float*)d_in[29];
  const float* smapwb  = (const float*)d_in[30];
  const float* m2fc1w = (const float*)d_in[31];
  const float* m2fc1b = (const float*)d_in[32];
  const float* m2dw0w = (const float*)d_in[33];
  const float* m2dw0b = (const float*)d_in[34];
  const float* m2dw1w = (const float*)d_in[35];
  const float* m2dw1b = (const float*)d_in[36];
  const float* m2dw2w = (const float*)d_in[37];
  const float* m2dw2b = (const float*)d_in[38];
  const float* m2fc2w = (const float*)d_in[39];
  const float* m2fc2b = (const float*)d_in[40];

  float* out = (float*)d_out;
  float* ws  = (float*)d_ws;
  float* LN  = ws;                        // 3,276,800 f
  float* QKV = ws + 3276800;              // 9,830,400 f  [sel][b][c][hw]
  float* ATT = ws;                        // reuse LN
  float* Hb  = ws + 3276800;              // reuse QKV region: 4,915,200 f
  float* Gb  = ws + 8192000;              // 2,457,600 f
  float* T1  = ws + 3276800;
  float* T2  = ws + 6553600;

  dim3 blk(256);

  // ---- Block 1: neighborhood attention ----
  ln2d_k<<<dim3(100, 4), blk, 0, stream>>>(x, n1w, n1b, LN);
  conv_qkv_k<<<dim3(100, 4, 6), blk, 0, stream>>>(LN, qkv0w, qkv0b, qkv1w, qkv1b, QKV);
  natt_k<<<dim3(25, 4, 8), blk, 0, stream>>>(QKV, ATT);
  conv1x1_k<128, 1><<<dim3(100, 4, 2), blk, 0, stream>>>(ATT, projw, projb, x, out, 128);

  // ---- Block 2: msconvstar (m1) ----
  ln2d_k<<<dim3(100, 4), blk, 0, stream>>>(out, n2w, n2b, LN);
  conv1x1_k<128, 0><<<dim3(100, 4, 3), blk, 0, stream>>>(LN, m1fc1w, m1fc1b, nullptr, Hb, 192);
  star_k<<<dim3(25, 4, 96), blk, 0, stream>>>(Hb, m1dw0w, m1dw0b, m1dw1w, m1dw1b, m1dw2w, m1dw2b, Gb);
  conv1x1_k<96, 1><<<dim3(100, 4, 2), blk, 0, stream>>>(Gb, m1fc2w, m1fc2b, out, out, 128);

  // ---- Block 3: cascaded sparse ----
  ln2d_k<<<dim3(100, 4), blk, 0, stream>>>(out, n3w, n3b, LN);
  dwg_k<1><<<dim3(25, 4, 128), blk, 0, stream>>>(LN, smadw0w, smadw0b, T1);
  dwg_k<2><<<dim3(25, 4, 128), blk, 0, stream>>>(T1, smadw1w, smadw1b, T2);
  conv1x1_k<128, 1><<<dim3(100, 4, 2), blk, 0, stream>>>(T2, smapww, smapwb, out, out, 128);

  // ---- Block 4: msconvstar (m2) ----
  ln2d_k<<<dim3(100, 4), blk, 0, stream>>>(out, n4w, n4b, LN);
  conv1x1_k<128, 0><<<dim3(100, 4, 3), blk, 0, stream>>>(LN, m2fc1w, m2fc1b, nullptr, Hb, 192);
  star_k<<<dim3(25, 4, 96), blk, 0, stream>>>(Hb, m2dw0w, m2dw0b, m2dw1w, m2dw1b, m2dw2w, m2dw2b, Gb);
  conv1x1_k<96, 1><<<dim3(100, 4, 2), blk, 0, stream>>>(Gb, m2fc2w, m2fc2b, out, out, 128);
}